// Round 4
// baseline (118.366 us; speedup 1.0000x reference)
//
#include <hip/hip_runtime.h>

static constexpr float EPSF = 1e-6f;

// Coefficient table, float2-interleaved, lane-coherent for the main kernel:
//   C2[(set*3+ch)*1024 + k*32 + ln] = { p_k = 1/denom_k,  sn_k = -c*_k }
// Sets 0..5  : x-direction, t = 0.1*set,          dt = DT/2 = 0.05
// Sets 6..10 : y-direction, t = 0.1*(set-6)+0.05, dt = DT   = 0.10

__global__ __launch_bounds__(64) void coef_kernel(
    const float* __restrict__ alpha_base, const float* __restrict__ beta_base,
    const float* __restrict__ alpha_tc,   const float* __restrict__ beta_tc,
    float2* __restrict__ C2)
{
    int gid  = blockIdx.x * 64 + threadIdx.x;
    int pair = gid >> 5;          // (set,ch) pair, 0..32
    int ln   = gid & 31;
    if (pair >= 33) return;
    int set = pair / 3;
    int ch  = pair % 3;
    bool isX = (set < 6);
    float t  = isX ? 0.1f * (float)set : 0.1f * (float)(set - 6) + 0.05f;
    float dt = isX ? 0.05f : 0.1f;

    const float* bp; const float* tp; int stride;
    if (isX) { bp = alpha_base + (ch * 32 + ln) * 32; tp = alpha_tc + (ch * 32 + ln) * 32; stride = 1; }
    else     { bp = beta_base  + ch * 1024 + ln;      tp = beta_tc  + ch * 1024 + ln;      stride = 32; }

    float c[32];
    #pragma unroll
    for (int i = 0; i < 32; ++i)
        c[i] = fmaxf(fmaf(tp[i * stride], t, bp[i * stride]), EPSF);

    float cs[32];
    #pragma unroll
    for (int i = 0; i < 32; ++i) {
        float l = (i == 0)  ? c[0]  : c[i - 1];
        float r = (i == 31) ? c[31] : c[i + 1];
        cs[i] = (l + c[i] + r) / 3.0f * dt;
    }

    // Thomas coefficient recurrence: b_i = 1+2cs_i (ends 1+cs), a_i = c_i = -cs_i, a_0 := 0
    float p[32], sn[32];
    {
        float den = (1.0f + cs[0]) + EPSF;
        p[0]  = 1.0f / den;
        sn[0] = cs[0] * p[0];
        float sprev = -sn[0];
        #pragma unroll
        for (int i = 1; i < 32; ++i) {
            float bi = (i == 31) ? (1.0f + cs[31]) : fmaf(2.0f, cs[i], 1.0f);
            float ai = -cs[i];
            float dd = (bi - ai * sprev) + EPSF;
            float pi = 1.0f / dd;
            p[i]  = pi;
            float si = ai * pi;
            sn[i] = -si;
            sprev = si;
        }
    }

    float2* o = C2 + (set * 3 + ch) * 1024 + ln;
    #pragma unroll
    for (int k = 0; k < 32; ++k) o[k * 32] = make_float2(p[k], sn[k]);
}

// Batch-load coefficients into registers (lane-coherent dwordx2, no deps).
__device__ __forceinline__ void loadc(float p[32], float sn[32],
                                      const float2* __restrict__ c)
{
    #pragma unroll
    for (int k = 0; k < 32; ++k) { float2 v = c[k * 32]; p[k] = v.x; sn[k] = v.y; }
}

// Pure-VALU register Thomas solve (coefs already in registers).
__device__ __forceinline__ void solve_reg(float d[32], const float p[32], const float sn[32])
{
    float prev = d[0] * p[0];
    d[0] = prev;
    #pragma unroll
    for (int i = 1; i < 32; ++i) {
        prev = fmaf(sn[i], prev, d[i] * p[i]);   // 4-cyc chain; mul independent
        d[i] = prev;
    }
    #pragma unroll
    for (int i = 30; i >= 0; --i)
        d[i] = fmaf(sn[i], d[i + 1], d[i]);
}

// ---------------------------------------------------------------------------
// Main kernel: 256 threads = 8 slabs, each wave owns 2 slabs end-to-end
// (staging included) -> ZERO barriers; all sync is intra-wave lgkmcnt.
// Tile stride 34: rows 8B-aligned (b64 phases), cols conflict-free b32.
// ---------------------------------------------------------------------------
__global__ __launch_bounds__(256, 3) void diff_kernel(
    const float* __restrict__ u_in, float* __restrict__ u_out,
    const float2* __restrict__ C2, int blocksPerCh)
{
    __shared__ float tile[8 * 1088];   // 8 slabs, 32 rows x stride 34 = 34816 B
    const int tid = threadIdx.x;
    const int bid = blockIdx.x;
    const int ch  = bid / blocksPerCh;
    const int b0  = (bid % blocksPerCh) * 8;
    const int wv  = tid >> 6;          // wave 0..3
    const int l   = tid & 63;
    const int ls  = tid >> 5;          // local slab 0..7
    const int ln  = tid & 31;          // line index

    const float2* cb = C2 + ch * 1024 + ln;
    float p[32], sn[32];
    loadc(p, sn, cb);                  // set 0 coefs in flight
    __builtin_amdgcn_sched_barrier(0);

    // ---- stage this wave's 2 slabs (coalesced float4) ----
    {
        const int sp = b0 + wv * 2;
        #pragma unroll
        for (int j = 0; j < 8; ++j) {
            int q   = j * 64 + l;
            int sl  = q >> 8;          // 0..1
            int rem = q & 255;         // float4 index within slab
            const float4 v = reinterpret_cast<const float4*>(
                u_in + ((sp + sl) * 3 + ch) * 1024)[rem];
            float* dst = &tile[(wv * 2 + sl) * 1088 + (rem >> 3) * 34 + ((rem & 7) << 2)];
            dst[0] = v.x; dst[1] = v.y; dst[2] = v.z; dst[3] = v.w;
        }
    }

    float* tb = &tile[ls * 1088];
    float d[32];
    #pragma unroll
    for (int j = 0; j < 16; ++j) {
        float2 v = *(const float2*)(tb + ln * 34 + 2 * j);
        d[2 * j] = v.x; d[2 * j + 1] = v.y;
    }
    solve_reg(d, p, sn);               // x half-step, set 0

    const float2* cy = cb + 6 * 3072;  // y sets 6..10
    const float2* cx = cb + 1 * 3072;  // x sets 1..5

    for (int step = 0; step < 5; ++step) {
        // ---- y full-step ----
        loadc(p, sn, cy); cy += 3072;
        __builtin_amdgcn_sched_barrier(0);
        #pragma unroll
        for (int j = 0; j < 16; ++j)   // write rows (b64)
            *(float2*)(tb + ln * 34 + 2 * j) = make_float2(d[2 * j], d[2 * j + 1]);
        #pragma unroll
        for (int i = 0; i < 32; ++i)   // read columns (conflict-free b32)
            d[i] = tb[i * 34 + ln];
        solve_reg(d, p, sn);

        // ---- x half-step pair (sets step+1, shared coefs) ----
        loadc(p, sn, cx); cx += 3072;
        __builtin_amdgcn_sched_barrier(0);
        #pragma unroll
        for (int i = 0; i < 32; ++i)   // write columns
            tb[i * 34 + ln] = d[i];
        #pragma unroll
        for (int j = 0; j < 16; ++j) { // read rows (b64)
            float2 v = *(const float2*)(tb + ln * 34 + 2 * j);
            d[2 * j] = v.x; d[2 * j + 1] = v.y;
        }
        solve_reg(d, p, sn);
        if (step < 4) solve_reg(d, p, sn);
    }

    // ---- writeback (rows -> LDS, coalesced float4 out) ----
    #pragma unroll
    for (int j = 0; j < 16; ++j)
        *(float2*)(tb + ln * 34 + 2 * j) = make_float2(d[2 * j], d[2 * j + 1]);
    {
        const int sp = b0 + wv * 2;
        #pragma unroll
        for (int j = 0; j < 8; ++j) {
            int q   = j * 64 + l;
            int sl  = q >> 8;
            int rem = q & 255;
            const float* s_ = &tile[(wv * 2 + sl) * 1088 + (rem >> 3) * 34 + ((rem & 7) << 2)];
            float4 v; v.x = s_[0]; v.y = s_[1]; v.z = s_[2]; v.w = s_[3];
            reinterpret_cast<float4*>(u_out + ((sp + sl) * 3 + ch) * 1024)[rem] = v;
        }
    }
}

extern "C" void kernel_launch(void* const* d_in, const int* in_sizes, int n_in,
                              void* d_out, int out_size, void* d_ws, size_t ws_size,
                              hipStream_t stream)
{
    const float* u   = (const float*)d_in[0];
    const float* ab  = (const float*)d_in[1];
    const float* bb  = (const float*)d_in[2];
    const float* atc = (const float*)d_in[3];
    const float* btc = (const float*)d_in[4];
    float* out = (float*)d_out;
    float2* C2 = (float2*)d_ws;        // 33*1024 float2 = 270336 B

    const int B = in_sizes[0] / (3 * 32 * 32);   // 2048
    const int blocksPerCh = B / 8;               // 256

    coef_kernel<<<17, 64, 0, stream>>>(ab, bb, atc, btc, C2);
    diff_kernel<<<3 * blocksPerCh, 256, 0, stream>>>(u, out, C2, blocksPerCh);
}